// Round 2
// 647.637 us; speedup vs baseline: 1.1613x; 1.1613x over previous
//
#include <hip/hip_runtime.h>
#include <hip/hip_bf16.h>
#include <stdint.h>

// LPLRQuantizedLinear: B=8192 rows, N=M=4096, rank 64 (48 frozen + 16 ft).
// ALL float tensors are FP32 (per reference); Q_idxs int32; output FP32.
//
// Pipeline:
//   prep     : R_cat[64][4096] bf16 (ws), L_cat -> Wq[:, 4096:4160] bf16
//   decode   : Wq[:, :4096] = bf16(0.02 * grid[Q_idxs])      (f32 grid)
//   fwht_pre : h[:, :4096] = bf16(FWHT(x*SU)/64)             (f32 in, fp32 math)
//   tgemm    : Tpart = h @ R_cat^T (k-split 4, fp32 partials)
//   tconv    : h[:, 4096:4160] = bf16(sum Tpart)
//   mgemm    : d_out = f32( h[8192,4160] @ Wq[4096,4160]^T ) -- 256^2 2-phase/K-step
//   fwht_post: d_out = (FWHT(d_out)/64) * SV                 (f32 in-place)
//
// mgemm v2b: 256x256 tile, BK=32, 8 waves, ring-of-4 LDS K-slots (128 KiB),
// global_load_lds staging with T2 source-side XOR swizzle (conflict-free
// fragment ds_read_b128), counted vmcnt(8) (never 0 in main loop), raw
// s_barrier schedule, setprio(1) around MFMA clusters, bijective XCD swizzle.
// v2b hardening: const-correct AS(1) cast; sched_barrier(0) after counted
// waitcnt asm (rule #18 insurance).

typedef __bf16 bf16;
typedef __bf16 bf16x8 __attribute__((ext_vector_type(8)));
typedef float f32x4 __attribute__((ext_vector_type(4)));

#define KE 4160
#define NN 4096
#define MM 4096
#define BB 8192

// ---------------- prep: build R_cat (bf16) and L columns of Wq ----------------
__global__ void prep_kernel(const float* __restrict__ Lft, const float* __restrict__ Rft,
                            const float* __restrict__ Lres, const float* __restrict__ Rres,
                            bf16* __restrict__ Rcat, bf16* __restrict__ Wq) {
  int tid = blockIdx.x * 256 + threadIdx.x;   // 524288 total
  if (tid < 64 * 4096) {
    int r = tid >> 12, n = tid & 4095;
    float v = (r < 48) ? Rres[r * 4096 + n] : Rft[(r - 48) * 4096 + n];
    Rcat[tid] = (bf16)v;
  } else {
    int t2 = tid - 64 * 4096;
    int m = t2 >> 6, r = t2 & 63;
    float v = (r < 48) ? Lres[m * 48 + r] : Lft[m * 16 + (r - 48)];
    Wq[(size_t)m * KE + 4096 + r] = (bf16)v;
  }
}

// ---------------- decode: Wq[:, :4096] = bf16(0.02*grid[Q_idxs]) ----------------
__global__ void decode_kernel(const int* __restrict__ qidx, const float* __restrict__ grid,
                              bf16* __restrict__ Wq) {
  int tid = blockIdx.x * 256 + threadIdx.x;   // 4096*512 = 2M
  int m = tid >> 9, g = tid & 511;
  uint32_t idx = (uint32_t)qidx[tid];
  const float4* gp = (const float4*)(grid + (size_t)idx * 8);
  float4 w0 = gp[0], w1 = gp[1];
  bf16x8 o;
  o[0] = (bf16)(w0.x * 0.02f); o[1] = (bf16)(w0.y * 0.02f);
  o[2] = (bf16)(w0.z * 0.02f); o[3] = (bf16)(w0.w * 0.02f);
  o[4] = (bf16)(w1.x * 0.02f); o[5] = (bf16)(w1.y * 0.02f);
  o[6] = (bf16)(w1.z * 0.02f); o[7] = (bf16)(w1.w * 0.02f);
  *(bf16x8*)(Wq + (size_t)m * KE + g * 8) = o;
}

// LDS skew for the FWHT butterflies: pure storage permutation, breaks the
// power-of-2 bank aliasing of the strided stages (+1 bank per 32 words).
#define SK(i) ((i) + ((i) >> 5))

// ---------------- FWHT-4096 row-wise, f32 in -> bf16 out (pre, *SU before) ----------------
__global__ void fwht_pre_kernel(const float* __restrict__ src,
                                bf16* __restrict__ dst,
                                const float* __restrict__ SU) {
  __shared__ float buf[4224];
  const int row = blockIdx.x, t = threadIdx.x;
  const float4* sp = (const float4*)(src + (size_t)row * NN + t * 16);
  const float4* su = (const float4*)(SU + t * 16);
  float v[16];
#pragma unroll
  for (int q = 0; q < 4; ++q) {
    float4 a = sp[q], s = su[q];
    v[q * 4 + 0] = a.x * s.x; v[q * 4 + 1] = a.y * s.y;
    v[q * 4 + 2] = a.z * s.z; v[q * 4 + 3] = a.w * s.w;
  }
#pragma unroll
  for (int s = 1; s < 16; s <<= 1) {
#pragma unroll
    for (int i = 0; i < 16; ++i) {
      if (!(i & s)) { float a = v[i], b = v[i + s]; v[i] = a + b; v[i + s] = a - b; }
    }
  }
#pragma unroll
  for (int i = 0; i < 16; ++i) buf[SK(t * 16 + i)] = v[i];
  for (int s = 16; s < 4096; s <<= 1) {
    __syncthreads();
#pragma unroll
    for (int j = 0; j < 8; ++j) {
      int p = t + j * 256;
      int i = ((p & ~(s - 1)) << 1) | (p & (s - 1));
      float a = buf[SK(i)], b = buf[SK(i + s)];
      buf[SK(i)] = a + b; buf[SK(i + s)] = a - b;
    }
  }
  __syncthreads();
  bf16x8 o0, o1;
#pragma unroll
  for (int i = 0; i < 8; ++i) {
    o0[i] = (bf16)(buf[SK(t * 16 + i)] * 0.015625f);
    o1[i] = (bf16)(buf[SK(t * 16 + 8 + i)] * 0.015625f);
  }
  bf16* dp = dst + (size_t)row * KE + t * 16;
  *(bf16x8*)dp = o0;
  *(bf16x8*)(dp + 8) = o1;
}

// ---------------- FWHT-4096 row-wise, f32 in-place (post, *SV after) ----------------
__global__ void fwht_post_kernel(float* __restrict__ data, const float* __restrict__ SV) {
  __shared__ float buf[4224];
  const int row = blockIdx.x, t = threadIdx.x;
  float4* dp = (float4*)(data + (size_t)row * MM + t * 16);
  float v[16];
#pragma unroll
  for (int q = 0; q < 4; ++q) {
    float4 a = dp[q];
    v[q * 4 + 0] = a.x; v[q * 4 + 1] = a.y; v[q * 4 + 2] = a.z; v[q * 4 + 3] = a.w;
  }
#pragma unroll
  for (int s = 1; s < 16; s <<= 1) {
#pragma unroll
    for (int i = 0; i < 16; ++i) {
      if (!(i & s)) { float a = v[i], b = v[i + s]; v[i] = a + b; v[i + s] = a - b; }
    }
  }
#pragma unroll
  for (int i = 0; i < 16; ++i) buf[SK(t * 16 + i)] = v[i];
  for (int s = 16; s < 4096; s <<= 1) {
    __syncthreads();
#pragma unroll
    for (int j = 0; j < 8; ++j) {
      int p = t + j * 256;
      int i = ((p & ~(s - 1)) << 1) | (p & (s - 1));
      float a = buf[SK(i)], b = buf[SK(i + s)];
      buf[SK(i)] = a + b; buf[SK(i + s)] = a - b;
    }
  }
  __syncthreads();
  const float4* sv = (const float4*)(SV + t * 16);
#pragma unroll
  for (int q = 0; q < 4; ++q) {
    float4 s = sv[q];
    float4 o;
    o.x = buf[SK(t * 16 + q * 4 + 0)] * 0.015625f * s.x;
    o.y = buf[SK(t * 16 + q * 4 + 1)] * 0.015625f * s.y;
    o.z = buf[SK(t * 16 + q * 4 + 2)] * 0.015625f * s.z;
    o.w = buf[SK(t * 16 + q * 4 + 3)] * 0.015625f * s.w;
    dp[q] = o;
  }
}

// ---------------- tgemm: Tpart[split] = h @ R_cat^T ----------------
__global__ void __launch_bounds__(256) tgemm_kernel(const bf16* __restrict__ A,
                                                    const bf16* __restrict__ Bm,
                                                    float* __restrict__ Tpart) {
  __shared__ bf16 lA[128 * 32];
  __shared__ bf16 lB[64 * 32];
  const int t = threadIdx.x, w = t >> 6, l = t & 63;
  const int bmBlk = blockIdx.x;   // 64 row blocks
  const int split = blockIdx.y;   // 4 k-splits
  const int wm = w >> 1, wn = w & 1;
  f32x4 acc[4][2] = {};
  const int arow = t >> 1, acol = (t & 1) * 16;            // A staging: 128 rows x 32
  const bf16* pa = A + (size_t)(bmBlk * 128 + arow) * KE + acol;
  const int brow = (t & 127) >> 1, bcol = acol;            // B staging: 64 rows x 32
  const bf16* pb = Bm + (size_t)brow * 4096 + bcol;
  const int fr = l & 15, fk = (l >> 4) * 8;
  for (int kt = 0; kt < 32; ++kt) {
    const int k0 = (split * 32 + kt) * 32;
    bf16x8 a0 = *(const bf16x8*)(pa + k0);
    bf16x8 a1 = *(const bf16x8*)(pa + k0 + 8);
    *(bf16x8*)&lA[arow * 32 + acol] = a0;
    *(bf16x8*)&lA[arow * 32 + acol + 8] = a1;
    if (t < 128) {
      bf16x8 b0 = *(const bf16x8*)(pb + k0);
      bf16x8 b1 = *(const bf16x8*)(pb + k0 + 8);
      *(bf16x8*)&lB[brow * 32 + bcol] = b0;
      *(bf16x8*)&lB[brow * 32 + bcol + 8] = b1;
    }
    __syncthreads();
    bf16x8 af[4], bfr[2];
#pragma unroll
    for (int i = 0; i < 4; ++i) af[i] = *(const bf16x8*)&lA[(wm * 64 + i * 16 + fr) * 32 + fk];
#pragma unroll
    for (int i = 0; i < 2; ++i) bfr[i] = *(const bf16x8*)&lB[(wn * 32 + i * 16 + fr) * 32 + fk];
#pragma unroll
    for (int mi = 0; mi < 4; ++mi)
#pragma unroll
      for (int ni = 0; ni < 2; ++ni)
        acc[mi][ni] = __builtin_amdgcn_mfma_f32_16x16x32_bf16(af[mi], bfr[ni], acc[mi][ni], 0, 0, 0);
    __syncthreads();
  }
  float* out = Tpart + (size_t)split * BB * 64;
  const int orow = bmBlk * 128 + wm * 64 + (l >> 4) * 4;
  const int ocol = wn * 32 + (l & 15);
#pragma unroll
  for (int mi = 0; mi < 4; ++mi)
#pragma unroll
    for (int ni = 0; ni < 2; ++ni)
#pragma unroll
      for (int r = 0; r < 4; ++r)
        out[(size_t)(orow + mi * 16 + r) * 64 + ocol + ni * 16] = acc[mi][ni][r];
}

__global__ void tconv_kernel(const float* __restrict__ Tpart, bf16* __restrict__ h) {
  int i = blockIdx.x * 256 + threadIdx.x;   // 8192*64
  float s = Tpart[i] + Tpart[i + BB * 64] + Tpart[i + 2 * BB * 64] + Tpart[i + 3 * BB * 64];
  int row = i >> 6, c = i & 63;
  h[(size_t)row * KE + 4096 + c] = (bf16)s;
}

// ---------------- mgemm v2b: 256^2 counted-vmcnt schedule ----------------
// C[8192,4096] f32 = A[8192,4160] @ B[4096,4160]^T, bf16 MFMA.
// Ring of 4 K-step slots (BK=32): sA/sB [4][256*32] bf16 = 64 KiB each.
// T2 swizzle (within a 16 KiB slot): byte ^= ((byte>>7)&3)<<4
//   -> permutes the four 16B sub-chunks within each 64B row by row bits 1-2.
//   Fragment reads: 16 lanes/quarter-wave hit 8 distinct 16B slots x 2 lanes
//   = 2-way aliasing = free (m136). Applied to the global SOURCE address of
//   global_load_lds (LDS dest stays linear, m104/m173) and to ds_read offsets
//   (same involution both sides, rule #21).

__device__ __forceinline__ void gload16(const void* g, void* l) {
  __builtin_amdgcn_global_load_lds(
      (const __attribute__((address_space(1))) void*)g,
      (__attribute__((address_space(3))) void*)l, 16, 0, 0);
}

__device__ __forceinline__ void bar() {
  asm volatile("" ::: "memory");
  __builtin_amdgcn_s_barrier();
  asm volatile("" ::: "memory");
}

__global__ void __launch_bounds__(512, 2) mgemm_kernel(const bf16* __restrict__ A,
                                                       const bf16* __restrict__ B,
                                                       float* __restrict__ C) {
  __shared__ alignas(16) char sA[65536];   // 4 slots x 256x32 bf16
  __shared__ alignas(16) char sB[65536];
  const int t = threadIdx.x;
  const int w = t >> 6, l = t & 63;
  const int wm = w >> 2, wn = w & 3;           // 2M x 4N waves, per-wave 128x64
  // bijective XCD swizzle (512 blocks, 512%8==0): each XCD gets 4 bm x 16 bn
  const int bid = blockIdx.x;
  const int swzb = (bid & 7) * 64 + (bid >> 3);
  const int bm = swzb >> 4, bn = swzb & 15;

  // ---- staging precompute: chunk c = w*2+j covers LDS bytes [c*1024, +1024)
  // lane l writes 16B at c*1024 + l*16 (hardware: uniform base + lane*16).
  // Pre-swizzle the SOURCE so that swizzled ds_reads see the right data.
  const int c0 = w * 2, c1 = w * 2 + 1;
  const int lb0 = c0 * 1024 + l * 16;
  const int lb1 = c1 * 1024 + l * 16;
  const int sb0 = lb0 ^ (((lb0 >> 7) & 3) << 4);
  const int sb1 = lb1 ^ (((lb1 >> 7) & 3) << 4);
  const char* gA0 = (const char*)(A + (size_t)(bm * 256 + (sb0 >> 6)) * KE) + (sb0 & 63);
  const char* gA1 = (const char*)(A + (size_t)(bm * 256 + (sb1 >> 6)) * KE) + (sb1 & 63);
  const char* gB0 = (const char*)(B + (size_t)(bn * 256 + (sb0 >> 6)) * KE) + (sb0 & 63);
  const char* gB1 = (const char*)(B + (size_t)(bn * 256 + (sb1 >> 6)) * KE) + (sb1 & 63);

  // ---- fragment ds_read byte offsets (within a 16 KiB slot), swizzled
  const int fr = l & 15, fkb = (l >> 4) * 16;  // 16x16x32 frag: row=l&15, k=(l>>4)*8 elems
  int offA[8], offB[4];
#pragma unroll
  for (int mi = 0; mi < 8; ++mi) {
    int lb = (wm * 128 + mi * 16 + fr) * 64 + fkb;
    offA[mi] = lb ^ (((lb >> 7) & 3) << 4);
  }
#pragma unroll
  for (int ni = 0; ni < 4; ++ni) {
    int lb = (wn * 64 + ni * 16 + fr) * 64 + fkb;
    offB[ni] = lb ^ (((lb >> 7) & 3) << 4);
  }

  f32x4 acc[8][4] = {};

  // ---- prologue: stage K-steps 0,1,2 (12 loads); vmcnt(8) -> slot 0 landed
#pragma unroll
  for (int p = 0; p < 3; ++p) {
    gload16(gA0 + (size_t)p * 64, &sA[p * 16384 + c0 * 1024]);
    gload16(gA1 + (size_t)p * 64, &sA[p * 16384 + c1 * 1024]);
    gload16(gB0 + (size_t)p * 64, &sB[p * 16384 + c0 * 1024]);
    gload16(gB1 + (size_t)p * 64, &sB[p * 16384 + c1 * 1024]);
  }
  asm volatile("s_waitcnt vmcnt(8)" ::: "memory");
  __builtin_amdgcn_sched_barrier(0);
  bar();

  // ---- main loop: 130 K-steps of 32; 2 phases each (16 MFMA / phase / wave)
  // Steady state: slots i+2, i+3 in flight (8 loads); vmcnt(8) at phase B
  // guarantees slot i+1 landed before the end-of-iteration barrier.
  for (int i = 0; i < 130; ++i) {
    const int sbs = (i & 3) << 14;          // current slot base
    const int s3b = ((i + 3) & 3) << 14;    // stage target slot (consumed at i-1)
    const size_t ko = (size_t)(i + 3) << 6; // byte advance: 32 bf16 per K-step
    bf16x8 af[4], bv[4];
    // phase A: frags for M-half 0 + all B frags; stage A(i+3)
#pragma unroll
    for (int mi = 0; mi < 4; ++mi) af[mi] = *(const bf16x8*)&sA[sbs + offA[mi]];
#pragma unroll
    for (int ni = 0; ni < 4; ++ni) bv[ni] = *(const bf16x8*)&sB[sbs + offB[ni]];
    if (i < 127) {
      gload16(gA0 + ko, &sA[s3b + c0 * 1024]);
      gload16(gA1 + ko, &sA[s3b + c1 * 1024]);
    }
    bar();
    __builtin_amdgcn_s_setprio(1);
#pragma unroll
    for (int mi = 0; mi < 4; ++mi)
#pragma unroll
      for (int ni = 0; ni < 4; ++ni)
        acc[mi][ni] = __builtin_amdgcn_mfma_f32_16x16x32_bf16(af[mi], bv[ni], acc[mi][ni], 0, 0, 0);
    __builtin_amdgcn_s_setprio(0);
    bar();
    // phase B: frags for M-half 1; stage B(i+3); counted vmcnt (never 0 in-loop)
#pragma unroll
    for (int mi = 0; mi < 4; ++mi) af[mi] = *(const bf16x8*)&sA[sbs + offA[4 + mi]];
    if (i < 127) {
      gload16(gB0 + ko, &sB[s3b + c0 * 1024]);
      gload16(gB1 + ko, &sB[s3b + c1 * 1024]);
      asm volatile("s_waitcnt vmcnt(8)" ::: "memory");  // slot i+1 landed
      __builtin_amdgcn_sched_barrier(0);
    } else if (i == 127) {
      asm volatile("s_waitcnt vmcnt(4)" ::: "memory");  // slot 128 landed
      __builtin_amdgcn_sched_barrier(0);
    } else if (i == 128) {
      asm volatile("s_waitcnt vmcnt(0)" ::: "memory");  // slot 129 landed
      __builtin_amdgcn_sched_barrier(0);
    }
    bar();
    __builtin_amdgcn_s_setprio(1);
#pragma unroll
    for (int mi = 0; mi < 4; ++mi)
#pragma unroll
      for (int ni = 0; ni < 4; ++ni)
        acc[4 + mi][ni] = __builtin_amdgcn_mfma_f32_16x16x32_bf16(af[mi], bv[ni], acc[4 + mi][ni], 0, 0, 0);
    __builtin_amdgcn_s_setprio(0);
    bar();
  }

  // ---- epilogue: C write (same lane->C mapping as the verified 128^2 kernel)
  const int orow = bm * 256 + wm * 128 + ((l >> 4) << 2);
  const int ocol = bn * 256 + wn * 64 + (l & 15);
#pragma unroll
  for (int mi = 0; mi < 8; ++mi)
#pragma unroll
    for (int ni = 0; ni < 4; ++ni)
#pragma unroll
      for (int r = 0; r < 4; ++r)
        C[(size_t)(orow + mi * 16 + r) * MM + ocol + ni * 16] = acc[mi][ni][r];
}

extern "C" void kernel_launch(void* const* d_in, const int* in_sizes, int n_in,
                              void* d_out, int out_size, void* d_ws, size_t ws_size,
                              hipStream_t stream) {
  const float* x    = (const float*)d_in[0];
  const float* SU   = (const float*)d_in[1];
  const float* SV   = (const float*)d_in[2];
  const float* grid = (const float*)d_in[3];
  const float* Lft  = (const float*)d_in[4];
  const float* Rft  = (const float*)d_in[5];
  const float* Lres = (const float*)d_in[6];
  const float* Rres = (const float*)d_in[7];
  const int*   qidx = (const int*)d_in[10];
  float* out = (float*)d_out;

  char* ws = (char*)d_ws;
  bf16*  h     = (bf16*)ws;                                   // 8192*4160*2 = 68,157,440
  bf16*  Wq    = (bf16*)(ws + 68157440);                      // 4096*4160*2 = 34,078,720
  bf16*  Rcat  = (bf16*)(ws + 68157440 + 34078720);           // 64*4096*2   =    524,288
  float* Tpart = (float*)(ws + 68157440 + 34078720 + 524288); // 4*8192*64*4 =  8,388,608

  prep_kernel<<<2048, 256, 0, stream>>>(Lft, Rft, Lres, Rres, Rcat, Wq);
  decode_kernel<<<8192, 256, 0, stream>>>(qidx, grid, Wq);
  fwht_pre_kernel<<<8192, 256, 0, stream>>>(x, h, SU);
  tgemm_kernel<<<dim3(64, 4), 256, 0, stream>>>(h, Rcat, Tpart);
  tconv_kernel<<<2048, 256, 0, stream>>>(Tpart, h);
  mgemm_kernel<<<512, 512, 0, stream>>>(h, Wq, out);
  fwht_post_kernel<<<8192, 256, 0, stream>>>(out, SV);
}